// Round 5
// baseline (183.593 us; speedup 1.0000x reference)
//
#include <hip/hip_runtime.h>
#include <stdint.h>

#define HIDDEN 768
#define EMBED  512
#define BATCH  16
#define SEQ    512
#define NWORDS (BATCH*SEQ)      // 8192
#define PAD_FLAT_IDX 2047       // flat index of words[0, 511, 3]
#define NEG_SLOPE 0.1f

__device__ __forceinline__ unsigned short f2bf(float f) {
    unsigned int x = __float_as_uint(f);
    unsigned int r = x + 0x7fffu + ((x >> 16) & 1u);
    return (unsigned short)(r >> 16);
}

// ---------------------------------------------------------------------------
// Kernel 1 (prep): blocks 0..15 -> per-batch stable-compaction scan (dest);
// blocks 16..399 -> w_ffn [768,512] f32 -> wt [512,768] bf16 N-major.
// (identical to round-2's prep — part of the best measured config)
// ---------------------------------------------------------------------------
__global__ __launch_bounds__(256) void prep_kernel(const int* __restrict__ words,
                                                   const float* __restrict__ w,
                                                   int* __restrict__ dest,
                                                   unsigned short* __restrict__ wt) {
    if (blockIdx.x < BATCH) {
        int b = blockIdx.x;
        int t = threadIdx.x;          // 0..255; handles words 2t, 2t+1
        int s0 = 2 * t, s1 = 2 * t + 1;
        int4 wa = ((const int4*)words)[b * SEQ + s0];
        int4 wb = ((const int4*)words)[b * SEQ + s1];
        bool v0 = (wa.x | wa.y | wa.z | wa.w) != 0;
        bool v1 = (wb.x | wb.y | wb.z | wb.w) != 0;

        unsigned long long m0 = __ballot(v0);
        unsigned long long m1 = __ballot(v1);
        int lane = t & 63;
        int wave = t >> 6;            // 0..3
        unsigned long long below = (1ull << lane) - 1ull;
        int pre = __popcll(m0 & below) + __popcll(m1 & below);
        __shared__ int wsum[4];
        if (lane == 0) wsum[wave] = __popcll(m0) + __popcll(m1);
        __syncthreads();
        int off = 0, tot = 0;
#pragma unroll
        for (int i = 0; i < 4; ++i) {
            int x = wsum[i];
            if (i < wave) off += x;
            tot += x;
        }
        int vp0 = off + pre;
        int vp1 = vp0 + (v0 ? 1 : 0);
        int d0 = v0 ? vp0 : (tot + (s0 - vp0));   // bijective over [0,SEQ)
        int d1 = v1 ? vp1 : (tot + (s1 - vp1));
        dest[b * SEQ + s0] = b * SEQ + d0;
        dest[b * SEQ + s1] = b * SEQ + d1;
    } else {
        __shared__ float tile[32][33];
        int bid = blockIdx.x - BATCH;       // 0..383
        int k0 = (bid % (HIDDEN / 32)) * 32;
        int n0 = (bid / (HIDDEN / 32)) * 32;
        int tc = threadIdx.x & 31;
        int tr = threadIdx.x >> 5;          // 0..7
#pragma unroll
        for (int i = 0; i < 4; ++i) {
            int r = tr + i * 8;
            tile[r][tc] = w[(size_t)(k0 + r) * EMBED + n0 + tc];
        }
        __syncthreads();
#pragma unroll
        for (int i = 0; i < 4; ++i) {
            int r = tr + i * 8;             // n offset within tile
            wt[(size_t)(n0 + r) * HIDDEN + k0 + tc] = f2bf(tile[tc][r]);
        }
    }
}

// ---------------------------------------------------------------------------
// Kernel 2 (pool): identical to round-2's pool — 8192 blocks x 192 threads
// (max TLP for the latency-bound gather; rounds 3/4 proved low-block pools
// collapse to 1 wave/SIMD and regress). Direct coalesced row-major store.
// ---------------------------------------------------------------------------
__global__ __launch_bounds__(192) void pool_kernel(const int* __restrict__ words,
                                                   const float* __restrict__ table,
                                                   const int* __restrict__ dest,
                                                   unsigned short* __restrict__ xseq) {
    int word = blockIdx.x;        // 0..8191
    int t = threadIdx.x;          // 0..191
    int drow = dest[word];        // hoisted: overlaps gather latency
    int4 w4 = ((const int4*)words)[word];
    int cnt = (w4.x != 0) + (w4.y != 0) + (w4.z != 0) + (w4.w != 0);

    float ax = 0.f, ay = 0.f, az = 0.f, aw = 0.f;
    if (cnt == 0) {
        int pid = words[PAD_FLAT_IDX];
        float4 v = ((const float4*)(table + (size_t)pid * HIDDEN))[t];
        ax = v.x; ay = v.y; az = v.z; aw = v.w;
    } else {
        if (w4.x != 0) { float4 v = ((const float4*)(table + (size_t)w4.x * HIDDEN))[t]; ax += v.x; ay += v.y; az += v.z; aw += v.w; }
        if (w4.y != 0) { float4 v = ((const float4*)(table + (size_t)w4.y * HIDDEN))[t]; ax += v.x; ay += v.y; az += v.z; aw += v.w; }
        if (w4.z != 0) { float4 v = ((const float4*)(table + (size_t)w4.z * HIDDEN))[t]; ax += v.x; ay += v.y; az += v.z; aw += v.w; }
        if (w4.w != 0) { float4 v = ((const float4*)(table + (size_t)w4.w * HIDDEN))[t]; ax += v.x; ay += v.y; az += v.z; aw += v.w; }
        float inv = 1.0f / (float)cnt;
        ax *= inv; ay *= inv; az *= inv; aw *= inv;
    }
    ushort4 o;
    o.x = f2bf(ax); o.y = f2bf(ay); o.z = f2bf(az); o.w = f2bf(aw);
    ((ushort4*)(xseq + (size_t)drow * HIDDEN))[t] = o;
}

// ---------------------------------------------------------------------------
// Kernel 3: LDS-FREE GEMM. C = leaky_relu(A @ Bt^T + bias).
// A=[8192,768] bf16 row-major, Bt=[512,768] bf16 N-major, out fp32.
// MFMA fragments are loaded DIRECTLY global->VGPR: a wave's fragment read
// (16 rows x 64 B, quads contiguous within row) covers 16 full cache lines
// -> fully coalesced. No LDS, no __syncthreads, no bank conflicts, no
// vmcnt(0) barrier drain; compiler pipelines loads across K freely.
// Block = 128(M) x 64(N); 4 waves stacked vertically (32 rows each, no
// duplicated A reads in-block). Grid 64x8 = 512 blocks. B is L2-resident.
// ---------------------------------------------------------------------------
typedef __attribute__((ext_vector_type(8))) short bf16x8;
typedef __attribute__((ext_vector_type(4))) float f32x4;

#define BM 128
#define BN 64

__global__ __launch_bounds__(256) void gemm_kernel(const unsigned short* __restrict__ A,
                                                   const unsigned short* __restrict__ Bt,
                                                   const float* __restrict__ bias,
                                                   float* __restrict__ out) {
    int tid  = threadIdx.x;
    int wave = tid >> 6;         // 0..3 -> 32-row slab
    int lane = tid & 63;
    int quad = lane >> 4;        // 0..3
    int l16  = lane & 15;
    int m0   = blockIdx.x * BM + wave * 32;
    int n0   = blockIdx.y * BN;

    f32x4 acc[2][4] = {};

    // lane's fragment base: row (m/n)+l16, k = quad*8
    const unsigned short* pa = A  + (size_t)(m0 + l16) * HIDDEN + quad * 8;
    const unsigned short* pb = Bt + (size_t)(n0 + l16) * HIDDEN + quad * 8;

#pragma unroll 2
    for (int k0 = 0; k0 < HIDDEN; k0 += 32) {
        bf16x8 af[2], bfr[4];
#pragma unroll
        for (int mt = 0; mt < 2; ++mt)
            af[mt] = *(const bf16x8*)(pa + (size_t)mt * 16 * HIDDEN + k0);
#pragma unroll
        for (int nt = 0; nt < 4; ++nt)
            bfr[nt] = *(const bf16x8*)(pb + (size_t)nt * 16 * HIDDEN + k0);

#pragma unroll
        for (int mt = 0; mt < 2; ++mt)
#pragma unroll
            for (int nt = 0; nt < 4; ++nt)
                acc[mt][nt] = __builtin_amdgcn_mfma_f32_16x16x32_bf16(
                    af[mt], bfr[nt], acc[mt][nt], 0, 0, 0);
    }

    // epilogue: D row = quad*4+r, col = l16 (verified layout, rounds 1-4)
#pragma unroll
    for (int nt = 0; nt < 4; ++nt) {
        int col = n0 + nt * 16 + l16;
        float bv = bias[col];
#pragma unroll
        for (int mt = 0; mt < 2; ++mt) {
            int rbase = m0 + mt * 16 + quad * 4;
#pragma unroll
            for (int r = 0; r < 4; ++r) {
                float v = acc[mt][nt][r] + bv;
                v = (v > 0.f) ? v : v * NEG_SLOPE;
                out[(size_t)(rbase + r) * EMBED + col] = v;
            }
        }
    }
}

// ---------------------------------------------------------------------------
extern "C" void kernel_launch(void* const* d_in, const int* in_sizes, int n_in,
                              void* d_out, int out_size, void* d_ws, size_t ws_size,
                              hipStream_t stream) {
    (void)in_sizes; (void)n_in; (void)out_size; (void)ws_size;
    const int*   words = (const int*)d_in[0];
    const float* table = (const float*)d_in[1];
    const float* wffn  = (const float*)d_in[2];
    const float* bffn  = (const float*)d_in[3];
    float* out = (float*)d_out;

    char* ws = (char*)d_ws;
    unsigned short* xseq = (unsigned short*)ws;                       // 12582912 B
    unsigned short* wt   = (unsigned short*)(ws + 12582912);          //   786432 B
    int*            dest = (int*)(ws + 12582912 + 786432);            //    32768 B

    prep_kernel<<<BATCH + (HIDDEN / 32) * (EMBED / 32), 256, 0, stream>>>(words, wffn, dest, wt);
    pool_kernel<<<NWORDS, 192, 0, stream>>>(words, table, dest, xseq);
    gemm_kernel<<<dim3(NWORDS / BM, EMBED / BN), 256, 0, stream>>>(xseq, wt, bffn, out);
}

// Round 6
// 160.840 us; speedup vs baseline: 1.1415x; 1.1415x over previous
//
#include <hip/hip_runtime.h>
#include <stdint.h>

#define HIDDEN 768
#define EMBED  512
#define BATCH  16
#define SEQ    512
#define NWORDS (BATCH*SEQ)      // 8192
#define PAD_FLAT_IDX 2047       // flat index of words[0, 511, 3]
#define NEG_SLOPE 0.1f
#define NPOOLBLK 2048           // 4 words per block, 128 blocks per batch

__device__ __forceinline__ unsigned short f2bf(float f) {
    unsigned int x = __float_as_uint(f);
    unsigned int r = x + 0x7fffu + ((x >> 16) & 1u);
    return (unsigned short)(r >> 16);
}

// ---------------------------------------------------------------------------
// Kernel 1 (combo): blocks 0..2047 -> pool 4 words each (one per wave).
//   Step A: rebuild the block's batch validity mask (512 bits) from words
//           via 2 int4 loads/thread + ballots into LDS (words is L2-hot:
//           512 KB re-read 128x = 64 MB L2 traffic, ~2 us, overlapped).
//   Step B: per wave, prefix-popcount -> dest row (stable compaction), then
//           gather <=4 table rows (12 independent float4/lane), mean-pool,
//           bf16 -> coalesced row-major store to xseq[dest].
// blocks 2048..2431 -> w_ffn [768,512] f32 -> wt [512,768] bf16 N-major.
// TLP: 2048x4 = 8192 pooling waves (8/SIMD) — R3/R4 proved low-TLP pools
// collapse; this keeps R2's occupancy with 3x the per-lane ILP.
// ---------------------------------------------------------------------------
__global__ __launch_bounds__(256) void combo_kernel(const int* __restrict__ words,
                                                    const float* __restrict__ w,
                                                    const float* __restrict__ table,
                                                    unsigned short* __restrict__ xseq,
                                                    unsigned short* __restrict__ wt) {
    if (blockIdx.x < NPOOLBLK) {
        __shared__ unsigned long long mask[8];   // validity bits, seg i = words 64i..64i+63
        int b    = blockIdx.x >> 7;              // batch
        int wave = threadIdx.x >> 6;
        int lane = threadIdx.x & 63;

        // ---- Step A: batch validity mask ----
        int p0 = wave * 64 + lane;               // 0..255
        int p1 = p0 + 256;                       // 256..511
        int4 wa = ((const int4*)words)[b * SEQ + p0];
        int4 wb = ((const int4*)words)[b * SEQ + p1];
        unsigned long long mlo = __ballot((wa.x | wa.y | wa.z | wa.w) != 0);
        unsigned long long mhi = __ballot((wb.x | wb.y | wb.z | wb.w) != 0);
        if (lane == 0) { mask[wave] = mlo; mask[4 + wave] = mhi; }
        __syncthreads();

        // ---- Step B: this wave's word ----
        int s = (blockIdx.x & 127) * 4 + wave;   // wave-uniform word index
        int seg = s >> 6;
        int bit = s & 63;
        int vp = 0, tot = 0;
#pragma unroll
        for (int i = 0; i < 8; ++i) {
            unsigned long long m = mask[i];
            int c = __popcll(m);
            if (i < seg) vp += c;
            tot += c;
        }
        unsigned long long mseg = mask[seg];
        vp += __popcll(mseg & ((1ull << bit) - 1ull));
        bool valid = (mseg >> bit) & 1ull;
        int d = valid ? vp : (tot + (s - vp));   // stable; bijective over [0,SEQ)
        int drow = b * SEQ + d;

        int4 w4 = ((const int4*)words)[b * SEQ + s];
        int cnt = (w4.x != 0) + (w4.y != 0) + (w4.z != 0) + (w4.w != 0);

        float sx[3] = {0.f, 0.f, 0.f}, sy[3] = {0.f, 0.f, 0.f};
        float sz[3] = {0.f, 0.f, 0.f}, sw[3] = {0.f, 0.f, 0.f};
        if (cnt == 0) {
            int pid = words[PAD_FLAT_IDX];
            const float4* rp = (const float4*)(table + (size_t)pid * HIDDEN);
#pragma unroll
            for (int c = 0; c < 3; ++c) {
                float4 v = rp[lane + 64 * c];
                sx[c] = v.x; sy[c] = v.y; sz[c] = v.z; sw[c] = v.w;
            }
            cnt = 1;
        } else {
            int id[4] = {w4.x, w4.y, w4.z, w4.w};
#pragma unroll
            for (int j = 0; j < 4; ++j) {
                if (id[j] != 0) {                // wave-uniform branch
                    const float4* rp = (const float4*)(table + (size_t)id[j] * HIDDEN);
#pragma unroll
                    for (int c = 0; c < 3; ++c) {
                        float4 v = rp[lane + 64 * c];
                        sx[c] += v.x; sy[c] += v.y; sz[c] += v.z; sw[c] += v.w;
                    }
                }
            }
        }
        float inv = 1.0f / (float)cnt;
#pragma unroll
        for (int c = 0; c < 3; ++c) {
            ushort4 o;
            o.x = f2bf(sx[c] * inv); o.y = f2bf(sy[c] * inv);
            o.z = f2bf(sz[c] * inv); o.w = f2bf(sw[c] * inv);
            *(ushort4*)&xseq[(size_t)drow * HIDDEN + (lane + 64 * c) * 4] = o;
        }
    } else {
        // ---- transpose+downcast w[k][n] -> wt[n][k] (R2-verbatim) ----
        __shared__ float tile[32][33];
        int bid = blockIdx.x - NPOOLBLK;        // 0..383
        int k0 = (bid % (HIDDEN / 32)) * 32;
        int n0 = (bid / (HIDDEN / 32)) * 32;
        int tc = threadIdx.x & 31;
        int tr = threadIdx.x >> 5;              // 0..7
#pragma unroll
        for (int i = 0; i < 4; ++i) {
            int r = tr + i * 8;
            tile[r][tc] = w[(size_t)(k0 + r) * EMBED + n0 + tc];
        }
        __syncthreads();
#pragma unroll
        for (int i = 0; i < 4; ++i) {
            int r = tr + i * 8;                 // n offset within tile
            wt[(size_t)(n0 + r) * HIDDEN + k0 + tc] = f2bf(tile[tc][r]);
        }
    }
}

// ---------------------------------------------------------------------------
// Kernel 2: R2-VERBATIM GEMM (best measured config; R5 proved don't touch).
// C = leaky_relu(A @ Bt^T + bias). Tile 128x64x32, 4 waves 2x2,
// global_load_lds width=16 staging, grid 64x8 = 512 blocks -> 2/CU.
// ---------------------------------------------------------------------------
typedef __attribute__((ext_vector_type(8))) short bf16x8;
typedef __attribute__((ext_vector_type(4))) float f32x4;

__device__ __forceinline__ void load_lds16(const void* g, void* l) {
    __builtin_amdgcn_global_load_lds(
        (const __attribute__((address_space(1))) unsigned int*)g,
        (__attribute__((address_space(3))) unsigned int*)l,
        16, 0, 0);
}

#define BM 128
#define BN 64
#define BK 32

__global__ __launch_bounds__(256) void gemm_kernel(const unsigned short* __restrict__ A,
                                                   const unsigned short* __restrict__ Bt,
                                                   const float* __restrict__ bias,
                                                   float* __restrict__ out) {
    __shared__ unsigned short sA[BM * BK];   // 8 KB
    __shared__ unsigned short sB[BN * BK];   // 4 KB

    int tid  = threadIdx.x;
    int m0   = blockIdx.x * BM;
    int n0   = blockIdx.y * BN;
    int wave = tid >> 6;
    int lane = tid & 63;
    int wr   = wave >> 1;        // 0..1: 64-row slab
    int wc   = wave & 1;         // 0..1: 32-col slab
    int quad = lane >> 4;        // 0..3
    int l16  = lane & 15;

    f32x4 acc[4][2] = {};

    const unsigned short* ga0 = A  + (size_t)(m0 + (tid >> 2)) * HIDDEN + (tid & 3) * 8;
    const unsigned short* ga1 = A  + (size_t)(m0 + 64 + (tid >> 2)) * HIDDEN + (tid & 3) * 8;
    const unsigned short* gb  = Bt + (size_t)(n0 + (tid >> 2)) * HIDDEN + (tid & 3) * 8;

    for (int k0 = 0; k0 < HIDDEN; k0 += BK) {
        load_lds16(ga0 + k0, &sA[tid * 8]);
        load_lds16(ga1 + k0, &sA[(256 + tid) * 8]);
        load_lds16(gb  + k0, &sB[tid * 8]);
        __syncthreads();

        bf16x8 af[4], bfr[2];
#pragma unroll
        for (int mt = 0; mt < 4; ++mt)
            af[mt] = *(const bf16x8*)&sA[(wr * 64 + mt * 16 + l16) * BK + quad * 8];
#pragma unroll
        for (int nt = 0; nt < 2; ++nt)
            bfr[nt] = *(const bf16x8*)&sB[(wc * 32 + nt * 16 + l16) * BK + quad * 8];

#pragma unroll
        for (int mt = 0; mt < 4; ++mt)
#pragma unroll
            for (int nt = 0; nt < 2; ++nt)
                acc[mt][nt] = __builtin_amdgcn_mfma_f32_16x16x32_bf16(
                    af[mt], bfr[nt], acc[mt][nt], 0, 0, 0);
        __syncthreads();
    }

    // epilogue: D row = quad*4+r, col = l16 (verified layout, rounds 1-5)
#pragma unroll
    for (int nt = 0; nt < 2; ++nt) {
        int col = n0 + wc * 32 + nt * 16 + l16;
        float bv = bias[col];
#pragma unroll
        for (int mt = 0; mt < 4; ++mt) {
            int rbase = m0 + wr * 64 + mt * 16 + quad * 4;
#pragma unroll
            for (int r = 0; r < 4; ++r) {
                float v = acc[mt][nt][r] + bv;
                v = (v > 0.f) ? v : v * NEG_SLOPE;
                out[(size_t)(rbase + r) * EMBED + col] = v;
            }
        }
    }
}

// ---------------------------------------------------------------------------
extern "C" void kernel_launch(void* const* d_in, const int* in_sizes, int n_in,
                              void* d_out, int out_size, void* d_ws, size_t ws_size,
                              hipStream_t stream) {
    (void)in_sizes; (void)n_in; (void)out_size; (void)ws_size;
    const int*   words = (const int*)d_in[0];
    const float* table = (const float*)d_in[1];
    const float* wffn  = (const float*)d_in[2];
    const float* bffn  = (const float*)d_in[3];
    float* out = (float*)d_out;

    char* ws = (char*)d_ws;
    unsigned short* xseq = (unsigned short*)ws;                       // 12582912 B
    unsigned short* wt   = (unsigned short*)(ws + 12582912);          //   786432 B

    combo_kernel<<<NPOOLBLK + (HIDDEN / 32) * (EMBED / 32), 256, 0, stream>>>(
        words, wffn, table, xseq, wt);
    gemm_kernel<<<dim3(NWORDS / BM, EMBED / BN), 256, 0, stream>>>(xseq, wt, bffn, out);
}